// Round 4
// baseline (215.604 us; speedup 1.0000x reference)
//
#include <hip/hip_runtime.h>
#include <math.h>

#define BATCH   256
#define NQ      1000
#define NC      80
#define NDET    300
#define SCORE_TH 0.05f

// ---------------- Kernel A: per-query key (sigmoid bits | 0) + label ----------------
#define QB        128          // queries per block
#define CHUNKS_PB 8            // blocks per batch: ceil(1000/128)
#define A_THREADS 256
#define F4Q       20           // float4 chunks per query (80/4)

__global__ __launch_bounds__(A_THREADS) void rtdetr_phase1(
    const float* __restrict__ logits,   // [B, Q, C]
    unsigned int* __restrict__ keys,    // [B*Q]
    int* __restrict__ labs)             // [B*Q]
{
    __shared__ float s_val[QB * F4Q];   // per-chunk max      (10 KB)
    __shared__ int   s_cls[QB * F4Q];   // per-chunk argmax   (10 KB)

    const int bb = blockIdx.x;
    const int b  = bb >> 3;             // batch image
    const int cb = bb & 7;              // chunk within image
    const int q0 = cb * QB;
    const int nq  = min(QB, NQ - q0);   // 128, last chunk 104
    const int nf4 = nq * F4Q;

    const float4* g = (const float4*)(logits + (size_t)b * NQ * NC) + (size_t)q0 * F4Q;
    const int t = threadIdx.x;

    // perfectly coalesced: thread i loads float4 #(i), (i+256), ... within the block range
    #pragma unroll
    for (int k = 0; k < 10; ++k) {
        int j = t + k * A_THREADS;
        if (j < nf4) {
            float4 v = g[j];
            float bv = v.x; int bc = 0;          // strict > keeps FIRST index
            if (v.y > bv) { bv = v.y; bc = 1; }
            if (v.z > bv) { bv = v.z; bc = 2; }
            if (v.w > bv) { bv = v.w; bc = 3; }
            s_val[j] = bv;
            s_cls[j] = bc;
        }
    }
    __syncthreads();

    if (t < nq) {
        const float* rv = &s_val[t * F4Q];
        const int*   rc = &s_cls[t * F4Q];
        float bv = rv[0];
        int   bc = rc[0];                        // class = 4*i + rc[i]
        #pragma unroll
        for (int i = 1; i < F4Q; ++i) {
            float v = rv[i];
            if (v > bv) { bv = v; bc = 4 * i + rc[i]; }   // strict >: earliest chunk wins
        }
        // sigmoid is monotone: max(sigmoid(x)) == sigmoid(max(x)), same fp32 expr as ref
        float sc = 1.0f / (1.0f + expf(-bv));
        int q = b * NQ + q0 + t;
        keys[q] = (sc > SCORE_TH) ? __float_as_uint(sc) : 0u;  // bits monotone for sc>0
        labs[q] = bc;
    }
}

// ---------------- Kernel B: exact stable rank + emit ----------------
#define B_THREADS 1024
#define NWAVE     (B_THREADS / 64)

__global__ __launch_bounds__(B_THREADS) void rtdetr_phase2(
    const unsigned int* __restrict__ keys,  // [B*Q]
    const int* __restrict__ labs,           // [B*Q]
    const float* __restrict__ boxes,        // [B, Q, 4]
    const float* __restrict__ sizes,        // [B, 2] (h, w)
    float* __restrict__ out)                // scores | labels | boxes
{
    __shared__ __align__(8) uint2 s_cs[NQ];          // compacted (key, idx)
    __shared__ unsigned long long s_wmask[NWAVE];

    const int b    = blockIdx.x;
    const int t    = threadIdx.x;
    const int lane = t & 63;
    const int wid  = t >> 6;

    unsigned int myk = 0u;
    if (t < NQ) myk = keys[b * NQ + t];
    const bool valid = (myk != 0u);

    unsigned long long m = __ballot(valid);
    if (lane == 0) s_wmask[wid] = m;
    __syncthreads();

    int beforeWave = 0, V = 0;
    #pragma unroll
    for (int w = 0; w < NWAVE; ++w) {
        int c = __popcll(s_wmask[w]);
        if (w < wid) beforeWave += c;
        V += c;
    }
    const int pv = beforeWave + __popcll(m & ((1ull << lane) - 1ull)); // #valid idx < t

    if (valid) s_cs[pv] = make_uint2(myk, (unsigned int)t);
    __syncthreads();

    // valid: rank among valid by (key desc, idx asc); all valid keys > 0 = invalid key.
    // invalid: all share key 0; stable order -> V + #invalid before t.
    int rank;
    if (valid) {
        rank = 0;
        for (int j = 0; j < V; ++j) {
            uint2 c = s_cs[j];                       // broadcast LDS read
            rank += (c.x > myk) || (c.x == myk && (int)c.y < t);
        }
    } else {
        rank = V + (t - pv);                         // t >= NQ -> rank = t >= NQ, no write
    }

    if (rank < NDET) {                               // bijection: exactly 300 writers
        float* out_scores = out;
        float* out_labels = out + (size_t)BATCH * NDET;
        float* out_boxes  = out + (size_t)2 * BATCH * NDET;
        const int o = b * NDET + rank;

        if (valid) {
            out_scores[o] = __uint_as_float(myk);
            out_labels[o] = (float)labs[b * NQ + t];
            float4 bx = ((const float4*)boxes)[b * NQ + t];   // cx, cy, w, h
            const float img_h = sizes[2 * b + 0];
            const float img_w = sizes[2 * b + 1];
            float4 ob;
            ob.x = (bx.x - 0.5f * bx.z) * img_w;
            ob.y = (bx.y - 0.5f * bx.w) * img_h;
            ob.z = (bx.x + 0.5f * bx.z) * img_w;
            ob.w = (bx.y + 0.5f * bx.w) * img_h;
            ((float4*)out_boxes)[o] = ob;
        } else {
            out_scores[o] = 0.0f;
            out_labels[o] = -1.0f;
            ((float4*)out_boxes)[o] = make_float4(0.0f, 0.0f, 0.0f, 0.0f);
        }
    }
}

extern "C" void kernel_launch(void* const* d_in, const int* in_sizes, int n_in,
                              void* d_out, int out_size, void* d_ws, size_t ws_size,
                              hipStream_t stream) {
    const float* logits = (const float*)d_in[0];   // [256,1000,80]
    const float* boxes  = (const float*)d_in[1];   // [256,1000,4]
    const float* sizes  = (const float*)d_in[2];   // [256,2]
    float* out = (float*)d_out;                    // 460800 floats

    unsigned int* keys = (unsigned int*)d_ws;                       // 1 MB
    int*          labs = (int*)((char*)d_ws + BATCH * NQ * 4);      // 1 MB

    rtdetr_phase1<<<BATCH * CHUNKS_PB, A_THREADS, 0, stream>>>(logits, keys, labs);
    rtdetr_phase2<<<BATCH, B_THREADS, 0, stream>>>(keys, labs, boxes, sizes, out);
}

// Round 5
// 135.259 us; speedup vs baseline: 1.5940x; 1.5940x over previous
//
#include <hip/hip_runtime.h>
#include <math.h>

#define BATCH   256
#define NQ      1000
#define NC      80
#define NDET    300
#define SCORE_TH 0.05f

// ---------------- Kernel A: per-query packed key ----------------
// keys64[b*NQ+q] = (sigmoid_bits << 32) | ((1023 - q) << 10) | label
//   - sigmoid_bits = fp32 bits of sigmoid(max logit) if > 0.05, else 0
//     (positive fp32 bits are order-monotone; sigmoid is monotone so
//      max(sigmoid(x)) == sigmoid(max(x)), identical fp32 expression)
//   - (1023-q) makes u64-descending order break key ties by q ascending
//     (exactly jax.lax.top_k's stable order), label bits can't matter.
#define QB        128          // queries per block
#define A_THREADS 256
#define F4Q       20           // float4 chunks per query (80/4)

__global__ __launch_bounds__(A_THREADS) void rtdetr_phase1(
    const float* __restrict__ logits,          // [B, Q, C]
    unsigned long long* __restrict__ keys64)   // [B*Q]
{
    __shared__ float s_val[QB * F4Q];   // per-chunk max      (10 KB)
    __shared__ int   s_cls[QB * F4Q];   // per-chunk argmax   (10 KB)

    const int bb = blockIdx.x;
    const int b  = bb >> 3;             // batch image
    const int cb = bb & 7;              // chunk within image
    const int q0 = cb * QB;
    const int nq  = min(QB, NQ - q0);   // 128, last chunk 104
    const int nf4 = nq * F4Q;

    const float4* g = (const float4*)(logits + (size_t)b * NQ * NC) + (size_t)q0 * F4Q;
    const int t = threadIdx.x;

    // perfectly coalesced: thread i loads float4 #(i), (i+256), ...
    #pragma unroll
    for (int k = 0; k < 10; ++k) {
        int j = t + k * A_THREADS;
        if (j < nf4) {
            float4 v = g[j];
            float bv = v.x; int bc = 0;          // strict > keeps FIRST index
            if (v.y > bv) { bv = v.y; bc = 1; }
            if (v.z > bv) { bv = v.z; bc = 2; }
            if (v.w > bv) { bv = v.w; bc = 3; }
            s_val[j] = bv;
            s_cls[j] = bc;
        }
    }
    __syncthreads();

    if (t < nq) {
        const float* rv = &s_val[t * F4Q];
        const int*   rc = &s_cls[t * F4Q];
        float bv = rv[0];
        int   bc = rc[0];
        #pragma unroll
        for (int i = 1; i < F4Q; ++i) {
            float v = rv[i];
            if (v > bv) { bv = v; bc = 4 * i + rc[i]; }   // strict >: earliest chunk wins
        }
        float sc = 1.0f / (1.0f + expf(-bv));
        unsigned int key = (sc > SCORE_TH) ? __float_as_uint(sc) : 0u;
        int q = q0 + t;
        keys64[(size_t)b * NQ + q] =
            ((unsigned long long)key << 32) |
            ((unsigned int)(1023 - q) << 10) | (unsigned int)bc;
    }
}

// ---------------- Kernel B: bitonic sort (descending) + emit top-300 ----------------
#define B_THREADS 1024

__global__ __launch_bounds__(B_THREADS) void rtdetr_phase2(
    const unsigned long long* __restrict__ keys64,  // [B*Q]
    const float* __restrict__ boxes,                // [B, Q, 4]
    const float* __restrict__ sizes,                // [B, 2] (h, w)
    float* __restrict__ out)                        // scores | labels | boxes
{
    __shared__ unsigned long long s_k[B_THREADS];   // 8 KB

    const int b = blockIdx.x;
    const int t = threadIdx.x;

    // pads = 0: every real entry has nonzero low bits (1023-q >= 24), so pads sort last
    s_k[t] = (t < NQ) ? keys64[(size_t)b * NQ + t] : 0ull;
    __syncthreads();

    // bitonic sort, descending; 55 phases. u64 stride-1 LDS = 2-way bank alias (free).
    for (int k = 2; k <= B_THREADS; k <<= 1) {
        for (int j = k >> 1; j > 0; j >>= 1) {
            int ixj = t ^ j;
            if (ixj > t) {
                unsigned long long a = s_k[t];
                unsigned long long c = s_k[ixj];
                bool desc = ((t & k) == 0);
                if (desc ? (a < c) : (a > c)) { s_k[t] = c; s_k[ixj] = a; }
            }
            __syncthreads();
        }
    }

    // sorted position == exact stable rank; threads 0..299 emit
    if (t < NDET) {
        unsigned long long c = s_k[t];
        unsigned int key = (unsigned int)(c >> 32);

        float* out_scores = out;
        float* out_labels = out + (size_t)BATCH * NDET;
        float* out_boxes  = out + (size_t)2 * BATCH * NDET;
        const int o = b * NDET + t;

        if (key != 0u) {
            int lab = (int)(c & 0x3FFull);
            int idx = 1023 - (int)((c >> 10) & 0x3FFull);
            out_scores[o] = __uint_as_float(key);
            out_labels[o] = (float)lab;
            float4 bx = ((const float4*)boxes)[b * NQ + idx];   // cx, cy, w, h
            const float img_h = sizes[2 * b + 0];
            const float img_w = sizes[2 * b + 1];
            float4 ob;
            ob.x = (bx.x - 0.5f * bx.z) * img_w;
            ob.y = (bx.y - 0.5f * bx.w) * img_h;
            ob.z = (bx.x + 0.5f * bx.z) * img_w;
            ob.w = (bx.y + 0.5f * bx.w) * img_h;
            ((float4*)out_boxes)[o] = ob;
        } else {
            out_scores[o] = 0.0f;
            out_labels[o] = -1.0f;
            ((float4*)out_boxes)[o] = make_float4(0.0f, 0.0f, 0.0f, 0.0f);
        }
    }
}

extern "C" void kernel_launch(void* const* d_in, const int* in_sizes, int n_in,
                              void* d_out, int out_size, void* d_ws, size_t ws_size,
                              hipStream_t stream) {
    const float* logits = (const float*)d_in[0];   // [256,1000,80]
    const float* boxes  = (const float*)d_in[1];   // [256,1000,4]
    const float* sizes  = (const float*)d_in[2];   // [256,2]
    float* out = (float*)d_out;                    // 460800 floats

    unsigned long long* keys64 = (unsigned long long*)d_ws;   // 2 MB

    rtdetr_phase1<<<BATCH * 8, A_THREADS, 0, stream>>>(logits, keys64);
    rtdetr_phase2<<<BATCH, B_THREADS, 0, stream>>>(keys64, boxes, sizes, out);
}

// Round 6
// 133.706 us; speedup vs baseline: 1.6125x; 1.0116x over previous
//
#include <hip/hip_runtime.h>
#include <math.h>

#define BATCH   256
#define NQ      1000
#define NC      80
#define NDET    300
#define SCORE_TH 0.05f

typedef unsigned long long u64;

// ---------------- Kernel A: per-query packed key, no LDS ----------------
// keys64[b*NQ+q] = (sigmoid_bits << 32) | ((1023 - q) << 10) | label
//   sigmoid_bits = fp32 bits of sigmoid(max logit) if > 0.05 else 0
//   (positive fp32 bits order-monotone; sigmoid monotone so
//    max(sigmoid(x)) == sigmoid(max(x)), identical fp32 expression).
//   u64-descending == (score desc, q asc) == jax.lax.top_k stable order.
// 4 lanes per query; lane r reads interleaved chunks 4i+r so each load
// instruction covers contiguous 64B per query (good coalescing).
#define A_THREADS 256

__global__ __launch_bounds__(A_THREADS) void rtdetr_phase1(
    const float* __restrict__ logits,   // [B, Q, C]
    u64* __restrict__ keys64)           // [B*Q]
{
    const int t    = threadIdx.x;
    const int lane = t & 63;
    const int wid  = t >> 6;
    const int b    = blockIdx.x >> 4;                      // image
    const int q    = (blockIdx.x & 15) * 64 + wid * 16 + (lane >> 2);
    const int r    = lane & 3;

    if (q >= NQ) return;   // uniform per 4-lane group; shfl partners share fate

    const float4* g = (const float4*)(logits + (size_t)b * NQ * NC) + (size_t)q * 20;

    float bv = -1e30f;
    int   bc = 0;
    #pragma unroll
    for (int i = 0; i < 5; ++i) {
        float4 v = g[4 * i + r];
        int c = 16 * i + 4 * r;
        // strict >: within this lane classes ascend with i, so FIRST index wins
        if (v.x > bv) { bv = v.x; bc = c + 0; }
        if (v.y > bv) { bv = v.y; bc = c + 1; }
        if (v.z > bv) { bv = v.z; bc = c + 2; }
        if (v.w > bv) { bv = v.w; bc = c + 3; }
    }
    // merge the 4 partials; ties -> smaller class (jnp.argmax semantics)
    #pragma unroll
    for (int d = 1; d <= 2; d <<= 1) {
        float ov = __shfl_xor(bv, d);
        int   oc = __shfl_xor(bc, d);
        if (ov > bv || (ov == bv && oc < bc)) { bv = ov; bc = oc; }
    }
    if (r == 0) {
        float sc = 1.0f / (1.0f + expf(-bv));
        unsigned int key = (sc > SCORE_TH) ? __float_as_uint(sc) : 0u;
        keys64[(size_t)b * NQ + q] =
            ((u64)key << 32) | ((unsigned int)(1023 - q) << 10) | (unsigned int)bc;
    }
}

// ---------------- Kernel B: hybrid bitonic sort (descending) + emit ----------------
// j<64 exchanges via shfl_xor (no barrier, all lanes active);
// j>=64 via LDS (10 phases x 2 barriers).
#define B_THREADS 1024

__global__ __launch_bounds__(B_THREADS) void rtdetr_phase2(
    const u64* __restrict__ keys64,     // [B*Q]
    const float* __restrict__ boxes,    // [B, Q, 4]
    const float* __restrict__ sizes,    // [B, 2] (h, w)
    float* __restrict__ out)            // scores | labels | boxes
{
    __shared__ u64 s_k[B_THREADS];      // 8 KB

    const int b = blockIdx.x;
    const int t = threadIdx.x;

    // pads = 0 sort last: every real entry has (1023-q)<<10 >= 24<<10 > 0
    u64 v = (t < NQ) ? keys64[(size_t)b * NQ + t] : 0ull;

    for (int k = 2; k <= B_THREADS; k <<= 1) {
        for (int j = k >> 1; j > 0; j >>= 1) {
            u64 o;
            if (j >= 64) {
                s_k[t] = v;
                __syncthreads();
                o = s_k[t ^ j];
                __syncthreads();
            } else {
                o = __shfl_xor(v, j);
            }
            // element at lower pair-index takes max in descending region
            const bool takeMax = (((t & j) == 0) == ((t & k) == 0));
            if (takeMax ? (o > v) : (o < v)) v = o;
        }
    }

    // thread t now holds exact stable rank-t entry
    if (t < NDET) {
        unsigned int key = (unsigned int)(v >> 32);

        float* out_scores = out;
        float* out_labels = out + (size_t)BATCH * NDET;
        float* out_boxes  = out + (size_t)2 * BATCH * NDET;
        const int o = b * NDET + t;

        if (key != 0u) {
            int lab = (int)(v & 0x3FFull);
            int idx = 1023 - (int)((v >> 10) & 0x3FFull);
            out_scores[o] = __uint_as_float(key);
            out_labels[o] = (float)lab;
            float4 bx = ((const float4*)boxes)[b * NQ + idx];   // cx, cy, w, h
            const float img_h = sizes[2 * b + 0];
            const float img_w = sizes[2 * b + 1];
            float4 ob;
            ob.x = (bx.x - 0.5f * bx.z) * img_w;
            ob.y = (bx.y - 0.5f * bx.w) * img_h;
            ob.z = (bx.x + 0.5f * bx.z) * img_w;
            ob.w = (bx.y + 0.5f * bx.w) * img_h;
            ((float4*)out_boxes)[o] = ob;
        } else {
            out_scores[o] = 0.0f;
            out_labels[o] = -1.0f;
            ((float4*)out_boxes)[o] = make_float4(0.0f, 0.0f, 0.0f, 0.0f);
        }
    }
}

extern "C" void kernel_launch(void* const* d_in, const int* in_sizes, int n_in,
                              void* d_out, int out_size, void* d_ws, size_t ws_size,
                              hipStream_t stream) {
    const float* logits = (const float*)d_in[0];   // [256,1000,80]
    const float* boxes  = (const float*)d_in[1];   // [256,1000,4]
    const float* sizes  = (const float*)d_in[2];   // [256,2]
    float* out = (float*)d_out;                    // 460800 floats

    u64* keys64 = (u64*)d_ws;                      // 2 MB scratch

    rtdetr_phase1<<<BATCH * 16, A_THREADS, 0, stream>>>(logits, keys64);
    rtdetr_phase2<<<BATCH, B_THREADS, 0, stream>>>(keys64, boxes, sizes, out);
}

// Round 7
// 131.568 us; speedup vs baseline: 1.6387x; 1.0163x over previous
//
#include <hip/hip_runtime.h>
#include <math.h>

#define BATCH   256
#define NQ      1000
#define NC      80
#define NDET    300
#define THREADS 1024
#define SCORE_TH 0.05f

typedef unsigned long long u64;

// Fused: per-query argmax -> packed key in LDS -> hybrid bitonic sort -> emit.
// key = (sigmoid_bits << 32) | ((1023 - q) << 10) | label
//   sigmoid_bits = fp32 bits of sigmoid(max logit) if > 0.05 else 0
//   (positive fp32 bits are order-monotone; sigmoid is monotone so
//    max(sigmoid(x)) == sigmoid(max(x)), same fp32 expression as reference).
//   u64-descending == (score desc, q asc) == jax.lax.top_k's stable order;
//   label bits can never affect order (the (1023-q) field is unique).
__global__ __launch_bounds__(THREADS) void rtdetr_fused(
    const float* __restrict__ logits,   // [B, Q, C]
    const float* __restrict__ boxes,    // [B, Q, 4]
    const float* __restrict__ sizes,    // [B, 2] (h, w)
    float* __restrict__ out)            // scores | labels | boxes
{
    __shared__ u64    s_k[THREADS];     // 8 KB  (keys; doubles as sort scratch)
    __shared__ float4 s_box[NQ];        // 16 KB (this image's boxes row)

    const int b = blockIdx.x;
    const int t = threadIdx.x;

    // ---- stage boxes row into LDS (coalesced, one pass) ----
    if (t < NQ) s_box[t] = ((const float4*)boxes)[b * NQ + t];
    // pad keys so entries 1000..1023 sort last (all real keys have nonzero low bits)
    if (t >= NQ) s_k[t] = 0ull;

    // ---- phase A: 4-lane-per-query argmax over raw logits, 4 passes ----
    const int r = t & 3;                 // sub-slice within the 4-lane group
    const float4* gbase = (const float4*)(logits + (size_t)b * NQ * NC);
    #pragma unroll
    for (int p = 0; p < 4; ++p) {
        const int q = p * 256 + (t >> 2);
        if (q < NQ) {                    // uniform per 4-lane group
            const float4* g = gbase + (size_t)q * 20;
            float bv = -1e30f;
            int   bc = 0;
            #pragma unroll
            for (int i = 0; i < 5; ++i) {
                float4 v = g[4 * i + r];
                int c = 16 * i + 4 * r;
                // strict >: FIRST (lowest) class wins among equal logits
                if (v.x > bv) { bv = v.x; bc = c + 0; }
                if (v.y > bv) { bv = v.y; bc = c + 1; }
                if (v.z > bv) { bv = v.z; bc = c + 2; }
                if (v.w > bv) { bv = v.w; bc = c + 3; }
            }
            // merge 4 partials; ties -> smaller class (jnp.argmax semantics)
            #pragma unroll
            for (int d = 1; d <= 2; d <<= 1) {
                float ov = __shfl_xor(bv, d);
                int   oc = __shfl_xor(bc, d);
                if (ov > bv || (ov == bv && oc < bc)) { bv = ov; bc = oc; }
            }
            if (r == 0) {
                float sc = 1.0f / (1.0f + expf(-bv));
                unsigned int key = (sc > SCORE_TH) ? __float_as_uint(sc) : 0u;
                s_k[q] = ((u64)key << 32) |
                         ((unsigned int)(1023 - q) << 10) | (unsigned int)bc;
            }
        }
    }
    __syncthreads();

    // ---- phase B: hybrid bitonic sort, descending ----
    // j<64 via shfl (no barrier, all lanes active); j>=64 via LDS (10 x 2 barriers)
    u64 v = s_k[t];
    for (int k = 2; k <= THREADS; k <<= 1) {
        for (int j = k >> 1; j > 0; j >>= 1) {
            u64 o;
            if (j >= 64) {
                __syncthreads();         // protect previous reads of s_k
                s_k[t] = v;
                __syncthreads();
                o = s_k[t ^ j];
            } else {
                o = __shfl_xor(v, j);
            }
            const bool takeMax = (((t & j) == 0) == ((t & k) == 0));
            if (takeMax ? (o > v) : (o < v)) v = o;
        }
    }

    // ---- emit: thread t holds the exact stable rank-t entry ----
    if (t < NDET) {
        unsigned int key = (unsigned int)(v >> 32);

        float* out_scores = out;
        float* out_labels = out + (size_t)BATCH * NDET;
        float* out_boxes  = out + (size_t)2 * BATCH * NDET;
        const int o = b * NDET + t;

        if (key != 0u) {
            int lab = (int)(v & 0x3FFull);
            int idx = 1023 - (int)((v >> 10) & 0x3FFull);
            out_scores[o] = __uint_as_float(key);
            out_labels[o] = (float)lab;
            float4 bx = s_box[idx];                  // cx, cy, w, h (LDS gather)
            const float img_h = sizes[2 * b + 0];
            const float img_w = sizes[2 * b + 1];
            float4 ob;
            ob.x = (bx.x - 0.5f * bx.z) * img_w;
            ob.y = (bx.y - 0.5f * bx.w) * img_h;
            ob.z = (bx.x + 0.5f * bx.z) * img_w;
            ob.w = (bx.y + 0.5f * bx.w) * img_h;
            ((float4*)out_boxes)[o] = ob;
        } else {
            out_scores[o] = 0.0f;
            out_labels[o] = -1.0f;
            ((float4*)out_boxes)[o] = make_float4(0.0f, 0.0f, 0.0f, 0.0f);
        }
    }
}

extern "C" void kernel_launch(void* const* d_in, const int* in_sizes, int n_in,
                              void* d_out, int out_size, void* d_ws, size_t ws_size,
                              hipStream_t stream) {
    const float* logits = (const float*)d_in[0];   // [256,1000,80]
    const float* boxes  = (const float*)d_in[1];   // [256,1000,4]
    const float* sizes  = (const float*)d_in[2];   // [256,2]
    float* out = (float*)d_out;                    // 460800 floats

    rtdetr_fused<<<BATCH, THREADS, 0, stream>>>(logits, boxes, sizes, out);
}

// Round 8
// 131.376 us; speedup vs baseline: 1.6411x; 1.0015x over previous
//
#include <hip/hip_runtime.h>
#include <math.h>

#define BATCH   256
#define NQ      1000
#define NC      80
#define NDET    300
#define THREADS 1024
#define SCORE_TH 0.05f

typedef unsigned long long u64;

// Fused: per-query argmax -> packed key in LDS -> hybrid bitonic sort -> emit.
// key = (sigmoid_bits << 32) | ((1023 - q) << 10) | label
//   sigmoid_bits = fp32 bits of sigmoid(max logit) if > 0.05 else 0
//   (positive fp32 bits are order-monotone; sigmoid is monotone so
//    max(sigmoid(x)) == sigmoid(max(x)), same fp32 expression as reference).
//   u64-descending == (score desc, q asc) == jax.lax.top_k's stable order;
//   label bits can never affect order (the (1023-q) field is unique per q).
__global__ __launch_bounds__(THREADS) void rtdetr_fused(
    const float* __restrict__ logits,   // [B, Q, C]
    const float* __restrict__ boxes,    // [B, Q, 4]
    const float* __restrict__ sizes,    // [B, 2] (h, w)
    float* __restrict__ out)            // scores | labels | boxes
{
    __shared__ u64    s_k[THREADS];     // 8 KB
    __shared__ float4 s_box[NQ];        // 16 KB

    const int b = blockIdx.x;
    const int t = threadIdx.x;

    // stage boxes row (coalesced); pad keys 1000..1023 so they sort last
    if (t < NQ) s_box[t] = ((const float4*)boxes)[b * NQ + t];
    if (t >= NQ) s_k[t] = 0ull;

    const int r = t & 3;                // sub-slice within 4-lane group
    const int g = t >> 2;               // group id 0..255
    const float4* gbase = (const float4*)(logits + (size_t)b * NQ * NC);

    // ---- phase A: 2 superpasses x 2 queries; ALL loads unconditional ----
    // q for pass p = p*256 + g; only p=3 can exceed NQ-1 -> clamp address,
    // guard the store. Branch-free load window lets 10 dwordx4 cluster.
    #pragma unroll
    for (int pp = 0; pp < 2; ++pp) {
        const int qa = (2 * pp + 0) * 256 + g;          // always < NQ
        const int qb = (2 * pp + 1) * 256 + g;          // p=3 may be >= NQ
        const int qbc = min(qb, NQ - 1);

        const float4* A = gbase + (size_t)qa * 20;
        const float4* B = gbase + (size_t)qbc * 20;

        float4 va[5], vb[5];
        #pragma unroll
        for (int i = 0; i < 5; ++i) va[i] = A[4 * i + r];
        #pragma unroll
        for (int i = 0; i < 5; ++i) vb[i] = B[4 * i + r];

        // reduce query A
        {
            float bv = -1e30f; int bc = 0;
            #pragma unroll
            for (int i = 0; i < 5; ++i) {
                float4 v = va[i]; int c = 16 * i + 4 * r;
                if (v.x > bv) { bv = v.x; bc = c + 0; }   // strict >: lowest class wins
                if (v.y > bv) { bv = v.y; bc = c + 1; }
                if (v.z > bv) { bv = v.z; bc = c + 2; }
                if (v.w > bv) { bv = v.w; bc = c + 3; }
            }
            #pragma unroll
            for (int d = 1; d <= 2; d <<= 1) {
                float ov = __shfl_xor(bv, d);
                int   oc = __shfl_xor(bc, d);
                if (ov > bv || (ov == bv && oc < bc)) { bv = ov; bc = oc; }
            }
            if (r == 0) {
                float sc = 1.0f / (1.0f + expf(-bv));
                unsigned int key = (sc > SCORE_TH) ? __float_as_uint(sc) : 0u;
                s_k[qa] = ((u64)key << 32) |
                          ((unsigned int)(1023 - qa) << 10) | (unsigned int)bc;
            }
        }
        // reduce query B (store guarded by qb < NQ)
        {
            float bv = -1e30f; int bc = 0;
            #pragma unroll
            for (int i = 0; i < 5; ++i) {
                float4 v = vb[i]; int c = 16 * i + 4 * r;
                if (v.x > bv) { bv = v.x; bc = c + 0; }
                if (v.y > bv) { bv = v.y; bc = c + 1; }
                if (v.z > bv) { bv = v.z; bc = c + 2; }
                if (v.w > bv) { bv = v.w; bc = c + 3; }
            }
            #pragma unroll
            for (int d = 1; d <= 2; d <<= 1) {
                float ov = __shfl_xor(bv, d);
                int   oc = __shfl_xor(bc, d);
                if (ov > bv || (ov == bv && oc < bc)) { bv = ov; bc = oc; }
            }
            if (r == 0 && qb < NQ) {
                float sc = 1.0f / (1.0f + expf(-bv));
                unsigned int key = (sc > SCORE_TH) ? __float_as_uint(sc) : 0u;
                s_k[qb] = ((u64)key << 32) |
                          ((unsigned int)(1023 - qb) << 10) | (unsigned int)bc;
            }
        }
    }
    __syncthreads();

    // ---- phase B: hybrid bitonic sort, descending ----
    // j<64 via shfl (no barrier); j>=64 via LDS (10 phases x 2 barriers)
    u64 v = s_k[t];
    for (int k = 2; k <= THREADS; k <<= 1) {
        for (int j = k >> 1; j > 0; j >>= 1) {
            u64 o;
            if (j >= 64) {
                __syncthreads();          // protect previous reads of s_k
                s_k[t] = v;
                __syncthreads();
                o = s_k[t ^ j];
            } else {
                o = __shfl_xor(v, j);
            }
            const bool takeMax = (((t & j) == 0) == ((t & k) == 0));
            if (takeMax ? (o > v) : (o < v)) v = o;
        }
    }

    // ---- emit: thread t holds the exact stable rank-t entry ----
    if (t < NDET) {
        unsigned int key = (unsigned int)(v >> 32);

        float* out_scores = out;
        float* out_labels = out + (size_t)BATCH * NDET;
        float* out_boxes  = out + (size_t)2 * BATCH * NDET;
        const int o = b * NDET + t;

        if (key != 0u) {
            int lab = (int)(v & 0x3FFull);
            int idx = 1023 - (int)((v >> 10) & 0x3FFull);
            out_scores[o] = __uint_as_float(key);
            out_labels[o] = (float)lab;
            float4 bx = s_box[idx];                  // cx, cy, w, h (LDS gather)
            const float img_h = sizes[2 * b + 0];
            const float img_w = sizes[2 * b + 1];
            float4 ob;
            ob.x = (bx.x - 0.5f * bx.z) * img_w;
            ob.y = (bx.y - 0.5f * bx.w) * img_h;
            ob.z = (bx.x + 0.5f * bx.z) * img_w;
            ob.w = (bx.y + 0.5f * bx.w) * img_h;
            ((float4*)out_boxes)[o] = ob;
        } else {
            out_scores[o] = 0.0f;
            out_labels[o] = -1.0f;
            ((float4*)out_boxes)[o] = make_float4(0.0f, 0.0f, 0.0f, 0.0f);
        }
    }
}

extern "C" void kernel_launch(void* const* d_in, const int* in_sizes, int n_in,
                              void* d_out, int out_size, void* d_ws, size_t ws_size,
                              hipStream_t stream) {
    const float* logits = (const float*)d_in[0];   // [256,1000,80]
    const float* boxes  = (const float*)d_in[1];   // [256,1000,4]
    const float* sizes  = (const float*)d_in[2];   // [256,2]
    float* out = (float*)d_out;                    // 460800 floats

    rtdetr_fused<<<BATCH, THREADS, 0, stream>>>(logits, boxes, sizes, out);
}